// Round 1
// baseline (126.227 us; speedup 1.0000x reference)
//
#include <hip/hip_runtime.h>
#include <hip/hip_fp16.h>

// CosinePrediction, fp16 two-pass (R5):
//  Pass 1: L2-normalize rows of both tables (fp32 math), store fp16 rows
//          (128 B, line-aligned) into a single contiguous table in d_ws.
//          No per-row scales -> no scale gathers in pass 2.
//  Pass 2: per-edge gather, 8 lanes/edge, one dwordx4 (8 halves) per lane per
//          row -> each row read is one fully-used, line-aligned 128 B segment.
//          Dot via v_dot2_f32_f16 (fp32 accumulate), 3-step shfl reduce.
// vs int8+scales (R3 best, 124.4/125.5 us): equal-or-fewer fabric bytes per
// edge (256 B guaranteed vs 256-512 B incl. scale-line waste), no dependent
// post-reduce scale gather, better precision (absmax ~3e-4 vs 5.9e-3).
// Cost: pass-1 writes 13.6 -> 25.6 MB (~ +2 us HBM).
// Fallback: fused fp32 single-pass kernel if ws_size < 25.6 MB.

#define D 64
#define EPS 1e-12f

struct h4 { __half2 a, b; };  // 8 bytes: 4 halves

typedef _Float16 half2_t __attribute__((ext_vector_type(2)));

__device__ __forceinline__ float fdot2_acc(int a, int b, float c) {
#if __has_builtin(__builtin_amdgcn_fdot2)
    return __builtin_amdgcn_fdot2(__builtin_bit_cast(half2_t, a),
                                  __builtin_bit_cast(half2_t, b), c, false);
#else
    const __half2 ha = __builtin_bit_cast(__half2, a);
    const __half2 hb = __builtin_bit_cast(__half2, b);
    const float2 fa = __half22float2(ha);
    const float2 fb = __half22float2(hb);
    return c + fa.x * fb.x + fa.y * fb.y;
#endif
}

// ---------------- Pass 1: normalize both tables -> fp16 rows ----------------
// 16 lanes per row, one float4 in / 4 halves (8 B) out per lane.
// Rows [0,NU) -> user, [NU,NTOT) -> item; single contiguous output table.
__global__ __launch_bounds__(256) void normalize_f16_kernel(
    const float* __restrict__ h_user, const float* __restrict__ h_item,
    h4* __restrict__ tab, int NU, int NTOT)
{
    int tid  = blockIdx.x * blockDim.x + threadIdx.x;
    int row  = tid >> 4;
    int lane = tid & 15;
    if (row >= NTOT) return;

    const float* src = (row < NU) ? (h_user + (size_t)row * D)
                                  : (h_item + (size_t)(row - NU) * D);
    const float4 u = *(const float4*)(src + lane * 4);

    float ss = u.x * u.x + u.y * u.y + u.z * u.z + u.w * u.w;
    #pragma unroll
    for (int m = 8; m >= 1; m >>= 1) ss += __shfl_xor(ss, m, 16);

    const float inv = 1.0f / fmaxf(sqrtf(ss), EPS);  // 1/max(||x||,eps)

    h4 q;
    q.a = __floats2half2_rn(u.x * inv, u.y * inv);
    q.b = __floats2half2_rn(u.z * inv, u.w * inv);
    // wave writes 4 rows x 128 B = 512 B contiguous
    tab[(size_t)row * 16 + lane] = q;
}

// ---------------- Pass 2: edge gather + fp16 dot ----------------
// 8 lanes per edge; lane reads one int4 (8 halves) of each 128 B row.
__global__ __launch_bounds__(256) void cos_edge_f16_kernel(
    const int4* __restrict__ tab,
    const int* __restrict__ src_idx, const int* __restrict__ dst_idx,
    float* __restrict__ out, int NU, int E)
{
    int tid  = blockIdx.x * blockDim.x + threadIdx.x;
    int edge = tid >> 3;
    int lane = tid & 7;
    if (edge >= E) return;

    const int s = src_idx[edge];
    const int t = dst_idx[edge];

    const int4 a = tab[(size_t)s * 8 + lane];
    const int4 b = tab[((size_t)NU + (size_t)t) * 8 + lane];

    float acc = 0.0f;
    acc = fdot2_acc(a.x, b.x, acc);
    acc = fdot2_acc(a.y, b.y, acc);
    acc = fdot2_acc(a.z, b.z, acc);
    acc = fdot2_acc(a.w, b.w, acc);

    acc += __shfl_xor(acc, 1, 8);
    acc += __shfl_xor(acc, 2, 8);
    acc += __shfl_xor(acc, 4, 8);

    if (lane == 0) out[edge] = acc;
}

// ---------------- Fallback: fused fp32 single pass ----------------
__global__ __launch_bounds__(256) void cos_edge_f32_kernel(
    const float* __restrict__ h_user,
    const float* __restrict__ h_item,
    const int* __restrict__ src_idx,
    const int* __restrict__ dst_idx,
    float* __restrict__ out,
    int E)
{
    int tid  = blockIdx.x * blockDim.x + threadIdx.x;
    int edge = tid >> 4;
    int lane = tid & 15;
    if (edge >= E) return;

    int s = src_idx[edge];
    int t = dst_idx[edge];

    const float4 u = *(const float4*)(h_user + (size_t)s * D + lane * 4);
    const float4 v = *(const float4*)(h_item + (size_t)t * D + lane * 4);

    float dot = u.x * v.x + u.y * v.y + u.z * v.z + u.w * v.w;
    float uu  = u.x * u.x + u.y * u.y + u.z * u.z + u.w * u.w;
    float vv  = v.x * v.x + v.y * v.y + v.z * v.z + v.w * v.w;

    #pragma unroll
    for (int off = 8; off >= 1; off >>= 1) {
        dot += __shfl_down(dot, off, 16);
        uu  += __shfl_down(uu,  off, 16);
        vv  += __shfl_down(vv,  off, 16);
    }

    if (lane == 0) {
        float nup = fmaxf(sqrtf(uu), EPS);
        float nvp = fmaxf(sqrtf(vv), EPS);
        out[edge] = dot / (nup * nvp);
    }
}

extern "C" void kernel_launch(void* const* d_in, const int* in_sizes, int n_in,
                              void* d_out, int out_size, void* d_ws, size_t ws_size,
                              hipStream_t stream) {
    const float* h_user = (const float*)d_in[0];
    const float* h_item = (const float*)d_in[1];
    const int*   src    = (const int*)d_in[2];
    const int*   dst    = (const int*)d_in[3];
    float*       out    = (float*)d_out;

    const int NU = in_sizes[0] / D;
    const int NI = in_sizes[1] / D;
    const int E  = in_sizes[2];

    // ws layout: fp16 table, rows [0,NU)=user, [NU,NU+NI)=item, 128 B/row
    const size_t need = (size_t)(NU + NI) * D * sizeof(__half);

    if (ws_size >= need) {
        h4* tab = (h4*)d_ws;

        const int threads = 256;
        const int NTOT = NU + NI;
        int blocks1 = (NTOT * 16 + threads - 1) / threads;
        normalize_f16_kernel<<<blocks1, threads, 0, stream>>>(
            h_user, h_item, tab, NU, NTOT);

        int blocks2 = (int)(((long long)E * 8 + threads - 1) / threads);
        cos_edge_f16_kernel<<<blocks2, threads, 0, stream>>>(
            (const int4*)tab, src, dst, out, NU, E);
    } else {
        const int threads = 256;
        int blocks = (E * 16 + threads - 1) / threads;
        cos_edge_f32_kernel<<<blocks, threads, 0, stream>>>(
            h_user, h_item, src, dst, out, E);
    }
}

// Round 2
// 125.562 us; speedup vs baseline: 1.0053x; 1.0053x over previous
//
#include <hip/hip_runtime.h>
#include <hip/hip_fp16.h>

// CosinePrediction, fp16 two-pass, 2-edge-per-thread pass2 (R6):
//  Pass 1: L2-normalize rows of both tables (fp32 math), store fp16 rows
//          (128 B, line-aligned) into one contiguous table in d_ws.
//          ~12 us: HBM floor (read 51.2 MB fp32, write 25.6 MB fp16).
//  Pass 2: per-edge gather + fp16 dot (v_dot2_f32_f16). 8 lanes per EDGE-PAIR,
//          each thread handles 2 edges -> 4 independent 16 B row-gathers in
//          flight per thread (2x the MLP of R5), half the wave count.
// Rationale: R3(int8,64B rows)==R5(fp16,128B rows) in time => pass2 is bound
// by random LINE REQUESTS (2/edge), not bytes. This probes latency- vs
// request-rate-bound. If neutral, the structure is at its floor:
// fills(2x42us, harness) + pass1(HBM floor) + pass2(2 random lines/edge).
// Fallback: fused fp32 single-pass kernel if ws_size < 25.6 MB.

#define D 64
#define EPS 1e-12f

struct h4 { __half2 a, b; };  // 8 bytes: 4 halves

typedef _Float16 half2_t __attribute__((ext_vector_type(2)));

__device__ __forceinline__ float fdot2_acc(int a, int b, float c) {
#if __has_builtin(__builtin_amdgcn_fdot2)
    return __builtin_amdgcn_fdot2(__builtin_bit_cast(half2_t, a),
                                  __builtin_bit_cast(half2_t, b), c, false);
#else
    const __half2 ha = __builtin_bit_cast(__half2, a);
    const __half2 hb = __builtin_bit_cast(__half2, b);
    const float2 fa = __half22float2(ha);
    const float2 fb = __half22float2(hb);
    return c + fa.x * fb.x + fa.y * fb.y;
#endif
}

// ---------------- Pass 1: normalize both tables -> fp16 rows ----------------
// 16 lanes per row, one float4 in / 4 halves (8 B) out per lane.
// Rows [0,NU) -> user, [NU,NTOT) -> item; single contiguous output table.
__global__ __launch_bounds__(256) void normalize_f16_kernel(
    const float* __restrict__ h_user, const float* __restrict__ h_item,
    h4* __restrict__ tab, int NU, int NTOT)
{
    int tid  = blockIdx.x * blockDim.x + threadIdx.x;
    int row  = tid >> 4;
    int lane = tid & 15;
    if (row >= NTOT) return;

    const float* src = (row < NU) ? (h_user + (size_t)row * D)
                                  : (h_item + (size_t)(row - NU) * D);
    const float4 u = *(const float4*)(src + lane * 4);

    float ss = u.x * u.x + u.y * u.y + u.z * u.z + u.w * u.w;
    #pragma unroll
    for (int m = 8; m >= 1; m >>= 1) ss += __shfl_xor(ss, m, 16);

    const float inv = 1.0f / fmaxf(sqrtf(ss), EPS);  // 1/max(||x||,eps)

    h4 q;
    q.a = __floats2half2_rn(u.x * inv, u.y * inv);
    q.b = __floats2half2_rn(u.z * inv, u.w * inv);
    // wave writes 4 rows x 128 B = 512 B contiguous
    tab[(size_t)row * 16 + lane] = q;
}

// ---------------- Pass 2: edge-pair gather + fp16 dot ----------------
// 8 lanes per edge-PAIR; lane reads one int4 (8 halves) of each 128 B row,
// for two edges -> 4 independent outstanding gathers per thread.
__global__ __launch_bounds__(256) void cos_edge_f16x2_kernel(
    const int4* __restrict__ tab,
    const int* __restrict__ src_idx, const int* __restrict__ dst_idx,
    float* __restrict__ out, int NU, int E)
{
    int tid  = blockIdx.x * blockDim.x + threadIdx.x;
    int pair = tid >> 3;
    int lane = tid & 7;
    int e0 = pair << 1;
    if (e0 >= E) return;
    const int  e1   = e0 + 1;
    const bool has1 = (e1 < E);

    const int s0 = src_idx[e0];
    const int t0 = dst_idx[e0];
    const int s1 = has1 ? src_idx[e1] : s0;
    const int t1 = has1 ? dst_idx[e1] : t0;

    // 4 independent random 16 B loads (8-lane groups cover 128 B rows)
    const int4 a0 = tab[(size_t)s0 * 8 + lane];
    const int4 b0 = tab[((size_t)NU + (size_t)t0) * 8 + lane];
    const int4 a1 = tab[(size_t)s1 * 8 + lane];
    const int4 b1 = tab[((size_t)NU + (size_t)t1) * 8 + lane];

    float acc0 = 0.0f, acc1 = 0.0f;
    acc0 = fdot2_acc(a0.x, b0.x, acc0);
    acc0 = fdot2_acc(a0.y, b0.y, acc0);
    acc0 = fdot2_acc(a0.z, b0.z, acc0);
    acc0 = fdot2_acc(a0.w, b0.w, acc0);
    acc1 = fdot2_acc(a1.x, b1.x, acc1);
    acc1 = fdot2_acc(a1.y, b1.y, acc1);
    acc1 = fdot2_acc(a1.z, b1.z, acc1);
    acc1 = fdot2_acc(a1.w, b1.w, acc1);

    #pragma unroll
    for (int m = 1; m <= 4; m <<= 1) {
        acc0 += __shfl_xor(acc0, m, 8);
        acc1 += __shfl_xor(acc1, m, 8);
    }

    if (lane == 0) {
        out[e0] = acc0;
        if (has1) out[e1] = acc1;
    }
}

// ---------------- Fallback: fused fp32 single pass ----------------
__global__ __launch_bounds__(256) void cos_edge_f32_kernel(
    const float* __restrict__ h_user,
    const float* __restrict__ h_item,
    const int* __restrict__ src_idx,
    const int* __restrict__ dst_idx,
    float* __restrict__ out,
    int E)
{
    int tid  = blockIdx.x * blockDim.x + threadIdx.x;
    int edge = tid >> 4;
    int lane = tid & 15;
    if (edge >= E) return;

    int s = src_idx[edge];
    int t = dst_idx[edge];

    const float4 u = *(const float4*)(h_user + (size_t)s * D + lane * 4);
    const float4 v = *(const float4*)(h_item + (size_t)t * D + lane * 4);

    float dot = u.x * v.x + u.y * v.y + u.z * v.z + u.w * v.w;
    float uu  = u.x * u.x + u.y * u.y + u.z * u.z + u.w * u.w;
    float vv  = v.x * v.x + v.y * v.y + v.z * v.z + v.w * v.w;

    #pragma unroll
    for (int off = 8; off >= 1; off >>= 1) {
        dot += __shfl_down(dot, off, 16);
        uu  += __shfl_down(uu,  off, 16);
        vv  += __shfl_down(vv,  off, 16);
    }

    if (lane == 0) {
        float nup = fmaxf(sqrtf(uu), EPS);
        float nvp = fmaxf(sqrtf(vv), EPS);
        out[edge] = dot / (nup * nvp);
    }
}

extern "C" void kernel_launch(void* const* d_in, const int* in_sizes, int n_in,
                              void* d_out, int out_size, void* d_ws, size_t ws_size,
                              hipStream_t stream) {
    const float* h_user = (const float*)d_in[0];
    const float* h_item = (const float*)d_in[1];
    const int*   src    = (const int*)d_in[2];
    const int*   dst    = (const int*)d_in[3];
    float*       out    = (float*)d_out;

    const int NU = in_sizes[0] / D;
    const int NI = in_sizes[1] / D;
    const int E  = in_sizes[2];

    // ws layout: fp16 table, rows [0,NU)=user, [NU,NU+NI)=item, 128 B/row
    const size_t need = (size_t)(NU + NI) * D * sizeof(__half);

    if (ws_size >= need) {
        h4* tab = (h4*)d_ws;

        const int threads = 256;
        const int NTOT = NU + NI;
        int blocks1 = (NTOT * 16 + threads - 1) / threads;
        normalize_f16_kernel<<<blocks1, threads, 0, stream>>>(
            h_user, h_item, tab, NU, NTOT);

        const long long pairs = ((long long)E + 1) / 2;
        int blocks2 = (int)((pairs * 8 + threads - 1) / threads);
        cos_edge_f16x2_kernel<<<blocks2, threads, 0, stream>>>(
            (const int4*)tab, src, dst, out, NU, E);
    } else {
        const int threads = 256;
        int blocks = (E * 16 + threads - 1) / threads;
        cos_edge_f32_kernel<<<blocks, threads, 0, stream>>>(
            h_user, h_item, src, dst, out, E);
    }
}